// Round 1
// baseline (230.919 us; speedup 1.0000x reference)
//
#include <hip/hip_runtime.h>
#include <stdint.h>

// ---------- types ----------
typedef __bf16 bf16x8 __attribute__((ext_vector_type(8)));
typedef float f32x4 __attribute__((ext_vector_type(4)));
typedef unsigned short u16x4 __attribute__((ext_vector_type(4)));

static __device__ __forceinline__ unsigned short f2bf(float f) {
    union { float f; unsigned u; } v; v.f = f;
    unsigned r = (v.u + 0x7FFFu + ((v.u >> 16) & 1u)) >> 16;  // RNE
    return (unsigned short)r;
}

// ---------- fp32 -> bf16 elementwise (vectorized x4) ----------
__global__ void f32_to_bf16_kernel(const float* __restrict__ src,
                                   unsigned short* __restrict__ dst, int n4) {
    int i = blockIdx.x * blockDim.x + threadIdx.x;
    if (i >= n4) return;
    f32x4 v = ((const f32x4*)src)[i];
    u16x4 o;
    o.x = f2bf(v.x); o.y = f2bf(v.y); o.z = f2bf(v.z); o.w = f2bf(v.w);
    ((u16x4*)dst)[i] = o;
}

// ---------- W (512x512 fp32) -> Wt (bf16, transposed), z selects matrix ----------
__global__ void transpose_w_kernel(const float* __restrict__ W0,
                                   const float* __restrict__ W1,
                                   const float* __restrict__ W2,
                                   unsigned short* __restrict__ dst) {
    const float* W = (blockIdx.z == 0) ? W0 : (blockIdx.z == 1) ? W1 : W2;
    unsigned short* out = dst + (size_t)blockIdx.z * (512 * 512);
    __shared__ float tile[32][33];
    int bx = blockIdx.x * 32, by = blockIdx.y * 32;
    int tx = threadIdx.x, ty = threadIdx.y;  // 32 x 8
    #pragma unroll
    for (int r = 0; r < 32; r += 8) {
        tile[ty + r][tx] = W[(size_t)(by + ty + r) * 512 + (bx + tx)];
    }
    __syncthreads();
    #pragma unroll
    for (int r = 0; r < 32; r += 8) {
        out[(size_t)(bx + ty + r) * 512 + (by + tx)] = f2bf(tile[tx][ty + r]);
    }
}

// ---------- GEMM: D[m][n] = sum_k A[m*LDA+k] * B[n*LDB+k]; writes out[n*LDO+m]
// 128x128 block tile, BK=64, 256 threads (4 waves, 2x2), mfma_f32_16x16x32_bf16.
// XOR-swizzled 16B chunks in LDS: chunk(row,pos) at linear row*8 + (pos ^ (row&7)).
template<int LDA, int LDB, int LDO, bool BIAS, bool RELU, typename OT>
__global__ __launch_bounds__(256, 2)
void gemm_abT_ct(const unsigned short* __restrict__ A,
                 const unsigned short* __restrict__ B,
                 OT* __restrict__ out, const float* __restrict__ bias,
                 long batchA, long batchB, long batchO) {
    __shared__ unsigned short As[128 * 64];
    __shared__ unsigned short Bs[128 * 64];

    const int tid  = threadIdx.x;
    const int lane = tid & 63;
    const int wave = tid >> 6;
    const int quad = lane >> 4;
    const int l16  = lane & 15;
    const int wm   = wave & 1;
    const int wn   = wave >> 1;

    const int m0 = blockIdx.x * 128;
    const int n0 = blockIdx.y * 128;
    A   += (size_t)blockIdx.z * batchA;
    B   += (size_t)blockIdx.z * batchB;
    out += (size_t)blockIdx.z * batchO;

    // staging: thread t handles LDS chunk c = round*256 + t; row=c>>3 (=r*32+t>>3),
    // swizzled pos field = t&7 -> global pos = (t&7) ^ ((t>>3)&7)  (r*32 ≡ 0 mod 8)
    const int srow = tid >> 3;
    const int spos = (tid & 7) ^ (srow & 7);
    const unsigned short* aG = A + (size_t)(m0 + srow) * LDA + spos * 8;
    const unsigned short* bG = B + (size_t)(n0 + srow) * LDB + spos * 8;
    char* aL = (char*)As + tid * 16;   // wave-uniform base + lane*16 by construction
    char* bL = (char*)Bs + tid * 16;

    f32x4 acc[4][4];
    #pragma unroll
    for (int i = 0; i < 4; ++i) {
        #pragma unroll
        for (int j = 0; j < 4; ++j) {
            f32x4 z = {0.f, 0.f, 0.f, 0.f};
            acc[i][j] = z;
        }
    }

    #pragma unroll 1
    for (int kk = 0; kk < 8; ++kk) {   // K=512, BK=64
        const int ko = kk * 64;
        #pragma unroll
        for (int r = 0; r < 4; ++r) {
            __builtin_amdgcn_global_load_lds(
                (__attribute__((address_space(1))) void*)(uintptr_t)(aG + (size_t)(r * 32) * LDA + ko),
                (__attribute__((address_space(3))) void*)(aL + r * 4096), 16, 0, 0);
        }
        #pragma unroll
        for (int r = 0; r < 4; ++r) {
            __builtin_amdgcn_global_load_lds(
                (__attribute__((address_space(1))) void*)(uintptr_t)(bG + (size_t)(r * 32) * LDB + ko),
                (__attribute__((address_space(3))) void*)(bL + r * 4096), 16, 0, 0);
        }
        __syncthreads();   // compiler emits s_waitcnt vmcnt(0) before s_barrier

        #pragma unroll
        for (int ks = 0; ks < 2; ++ks) {
            bf16x8 af[4], bfr[4];
            #pragma unroll
            for (int i = 0; i < 4; ++i) {
                const int row = wm * 64 + i * 16 + l16;
                const int idx = row * 8 + ((ks * 4 + quad) ^ (row & 7));
                af[i] = *(const bf16x8*)((const char*)As + idx * 16);
            }
            #pragma unroll
            for (int j = 0; j < 4; ++j) {
                const int row = wn * 64 + j * 16 + l16;
                const int idx = row * 8 + ((ks * 4 + quad) ^ (row & 7));
                bfr[j] = *(const bf16x8*)((const char*)Bs + idx * 16);
            }
            #pragma unroll
            for (int i = 0; i < 4; ++i) {
                #pragma unroll
                for (int j = 0; j < 4; ++j) {
                    acc[i][j] = __builtin_amdgcn_mfma_f32_16x16x32_bf16(af[i], bfr[j], acc[i][j], 0, 0, 0);
                }
            }
        }
        __syncthreads();
    }

    // epilogue: C/D layout col=l16 (n-dim), row=quad*4+reg (m-dim); write out[n*LDO+m]
    #pragma unroll
    for (int i = 0; i < 4; ++i) {
        const int mb = m0 + wm * 64 + i * 16 + quad * 4;
        f32x4 bb = {0.f, 0.f, 0.f, 0.f};
        if constexpr (BIAS) bb = *(const f32x4*)(bias + mb);
        #pragma unroll
        for (int j = 0; j < 4; ++j) {
            const int n = n0 + wn * 64 + j * 16 + l16;
            f32x4 v = acc[i][j];
            if constexpr (BIAS) v += bb;
            if constexpr (RELU) {
                v.x = v.x > 0.f ? v.x : 0.f;
                v.y = v.y > 0.f ? v.y : 0.f;
                v.z = v.z > 0.f ? v.z : 0.f;
                v.w = v.w > 0.f ? v.w : 0.f;
            }
            if constexpr (sizeof(OT) == 4) {
                *(f32x4*)((float*)out + (size_t)n * LDO + mb) = v;
            } else {
                u16x4 o;
                o.x = f2bf(v.x); o.y = f2bf(v.y); o.z = f2bf(v.z); o.w = f2bf(v.w);
                *(u16x4*)((unsigned short*)out + (size_t)n * LDO + mb) = o;
            }
        }
    }
}

extern "C" void kernel_launch(void* const* d_in, const int* in_sizes, int n_in,
                              void* d_out, int out_size, void* d_ws, size_t ws_size,
                              hipStream_t stream) {
    (void)in_sizes; (void)n_in; (void)out_size; (void)ws_size;
    const float* X   = (const float*)d_in[0];
    const float* adj = (const float*)d_in[1];
    const float* W0  = (const float*)d_in[2];
    const float* b0  = (const float*)d_in[3];
    const float* W1  = (const float*)d_in[4];
    const float* b1  = (const float*)d_in[5];
    const float* W2  = (const float*)d_in[6];
    const float* b2  = (const float*)d_in[7];
    float* out = (float*)d_out;

    // workspace layout (bf16 buffers): adjB | bufH (X/h, node-major) | tmpT (feat-major) | Wt x3
    char* ws = (char*)d_ws;
    const size_t SZ = 16777216;  // 32*512*512*2
    unsigned short* adjB = (unsigned short*)(ws);
    unsigned short* bufH = (unsigned short*)(ws + SZ);
    unsigned short* tmpT = (unsigned short*)(ws + 2 * SZ);
    unsigned short* Wt   = (unsigned short*)(ws + 3 * SZ);
    const unsigned short* W0t = Wt;
    const unsigned short* W1t = Wt + 262144;
    const unsigned short* W2t = Wt + 2 * 262144;

    const int NE4 = (32 * 512 * 512) / 4;  // 2097152
    f32_to_bf16_kernel<<<NE4 / 256, 256, 0, stream>>>(X, bufH, NE4);
    f32_to_bf16_kernel<<<NE4 / 256, 256, 0, stream>>>(adj, adjB, NE4);
    transpose_w_kernel<<<dim3(16, 16, 3), dim3(32, 8), 0, stream>>>(W0, W1, W2, Wt);

    const long BATCH = 512L * 512L;

    // layer 0: tmpT[e][node] = (h @ W0);  h = relu(adj @ tmp + b0) node-major
    gemm_abT_ct<512, 512, 16384, false, false, unsigned short>
        <<<dim3(128, 4, 1), 256, 0, stream>>>(bufH, W0t, tmpT, nullptr, 0, 0, 0);
    gemm_abT_ct<16384, 512, 512, true, true, unsigned short>
        <<<dim3(4, 4, 32), 256, 0, stream>>>(tmpT, adjB, bufH, b0, 512, BATCH, BATCH);
    // layer 1
    gemm_abT_ct<512, 512, 16384, false, false, unsigned short>
        <<<dim3(128, 4, 1), 256, 0, stream>>>(bufH, W1t, tmpT, nullptr, 0, 0, 0);
    gemm_abT_ct<16384, 512, 512, true, true, unsigned short>
        <<<dim3(4, 4, 32), 256, 0, stream>>>(tmpT, adjB, bufH, b1, 512, BATCH, BATCH);
    // layer 2 (no relu, fp32 out)
    gemm_abT_ct<512, 512, 16384, false, false, unsigned short>
        <<<dim3(128, 4, 1), 256, 0, stream>>>(bufH, W2t, tmpT, nullptr, 0, 0, 0);
    gemm_abT_ct<16384, 512, 512, true, false, float>
        <<<dim3(4, 4, 32), 256, 0, stream>>>(tmpT, adjB, out, b2, 512, BATCH, BATCH);
}

// Round 2
// 223.047 us; speedup vs baseline: 1.0353x; 1.0353x over previous
//
#include <hip/hip_runtime.h>
#include <stdint.h>

// ---------- types ----------
typedef __bf16 bf16x8 __attribute__((ext_vector_type(8)));
typedef float f32x4 __attribute__((ext_vector_type(4)));
typedef unsigned short u16x4 __attribute__((ext_vector_type(4)));

static __device__ __forceinline__ unsigned short f2bf(float f) {
    union { float f; unsigned u; } v; v.f = f;
    unsigned r = (v.u + 0x7FFFu + ((v.u >> 16) & 1u)) >> 16;  // RNE
    return (unsigned short)r;
}

// ---------- fused prep: convert X, convert adj, transpose W0/W1/W2 ----------
// grid.x = 8192 (X) + 8192 (adj) + 768 (W transpose tiles), 256 threads
__global__ void prep_kernel(const float* __restrict__ X,
                            const float* __restrict__ adj,
                            const float* __restrict__ W0,
                            const float* __restrict__ W1,
                            const float* __restrict__ W2,
                            unsigned short* __restrict__ bufH,
                            unsigned short* __restrict__ adjB,
                            unsigned short* __restrict__ Wt) {
    const int bid = blockIdx.x;
    const int t = threadIdx.x;
    if (bid < 16384) {
        const float* src = (bid < 8192) ? X : adj;
        unsigned short* dst = (bid < 8192) ? bufH : adjB;
        const int i = (bid & 8191) * 256 + t;
        f32x4 v = ((const f32x4*)src)[i];
        u16x4 o;
        o.x = f2bf(v.x); o.y = f2bf(v.y); o.z = f2bf(v.z); o.w = f2bf(v.w);
        ((u16x4*)dst)[i] = o;
    } else {
        const int wb = bid - 16384;          // 0..767
        const int z = wb >> 8;               // which W
        const int tile = wb & 255;           // 16x16 tiles of 32x32
        const float* W = (z == 0) ? W0 : (z == 1) ? W1 : W2;
        unsigned short* out = Wt + (size_t)z * (512 * 512);
        __shared__ float tileS[32][33];
        const int bx = (tile & 15) * 32, by = (tile >> 4) * 32;
        const int tx = t & 31, ty = t >> 5;  // 32 x 8
        #pragma unroll
        for (int r = 0; r < 32; r += 8)
            tileS[ty + r][tx] = W[(size_t)(by + ty + r) * 512 + (bx + tx)];
        __syncthreads();
        #pragma unroll
        for (int r = 0; r < 32; r += 8)
            out[(size_t)(bx + ty + r) * 512 + (by + tx)] = f2bf(tileS[tx][ty + r]);
    }
}

// ---------- GEMM: D[m][n] = sum_k A[m*LDA+k] * B[n*LDB+k]; writes out[n*LDO+m]
// 128x128 block tile, BK=128 (4 K-iters at K=512), 256 threads (4 waves, 2x2),
// mfma_f32_16x16x32_bf16. LDS: 16B chunks, 16 chunks/row, XOR swizzle
// chunk(row,pos) at row*16 + (pos ^ (row & 15)).
template<int LDA, int LDB, int LDO, bool BIAS, bool RELU, typename OT>
__global__ __launch_bounds__(256, 2)
void gemm_abT_ct(const unsigned short* __restrict__ A,
                 const unsigned short* __restrict__ B,
                 OT* __restrict__ out, const float* __restrict__ bias,
                 long batchA, long batchB, long batchO) {
    __shared__ unsigned short As[128 * 128];   // 32 KB
    __shared__ unsigned short Bs[128 * 128];   // 32 KB

    const int tid  = threadIdx.x;
    const int lane = tid & 63;
    const int wave = tid >> 6;
    const int quad = lane >> 4;
    const int l16  = lane & 15;
    const int wm   = wave & 1;
    const int wn   = wave >> 1;

    const int m0 = blockIdx.x * 128;
    const int n0 = blockIdx.y * 128;
    A   += (size_t)blockIdx.z * batchA;
    B   += (size_t)blockIdx.z * batchB;
    out += (size_t)blockIdx.z * batchO;

    // staging: round r, thread t -> chunk c = r*256+t; row = c>>4 = r*16 + (t>>4),
    // swizzled pos = (c&15) ^ (row&15) = (t&15) ^ (t>>4)   (r*16 ≡ 0 mod 16)
    const int trow = tid >> 4;                    // 0..15
    const int tpos = (tid & 15) ^ trow;           // r-independent
    const unsigned short* aG = A + (size_t)(m0 + trow) * LDA + tpos * 8;
    const unsigned short* bG = B + (size_t)(n0 + trow) * LDB + tpos * 8;
    char* aL = (char*)As + tid * 16;   // wave-uniform base + lane*16
    char* bL = (char*)Bs + tid * 16;

    f32x4 acc[4][4];
    #pragma unroll
    for (int i = 0; i < 4; ++i)
        #pragma unroll
        for (int j = 0; j < 4; ++j) {
            f32x4 z = {0.f, 0.f, 0.f, 0.f};
            acc[i][j] = z;
        }

    #pragma unroll 1
    for (int kk = 0; kk < 4; ++kk) {   // K=512, BK=128
        const int ko = kk * 128;
        #pragma unroll
        for (int r = 0; r < 8; ++r) {
            __builtin_amdgcn_global_load_lds(
                (__attribute__((address_space(1))) void*)(uintptr_t)(aG + (size_t)(r * 16) * LDA + ko),
                (__attribute__((address_space(3))) void*)(aL + r * 4096), 16, 0, 0);
        }
        #pragma unroll
        for (int r = 0; r < 8; ++r) {
            __builtin_amdgcn_global_load_lds(
                (__attribute__((address_space(1))) void*)(uintptr_t)(bG + (size_t)(r * 16) * LDB + ko),
                (__attribute__((address_space(3))) void*)(bL + r * 4096), 16, 0, 0);
        }
        __syncthreads();

        #pragma unroll
        for (int ks = 0; ks < 4; ++ks) {
            bf16x8 af[4], bfr[4];
            #pragma unroll
            for (int i = 0; i < 4; ++i) {
                const int row = wm * 64 + i * 16 + l16;
                const int idx = row * 16 + ((ks * 4 + quad) ^ (row & 15));
                af[i] = *(const bf16x8*)((const char*)As + idx * 16);
            }
            #pragma unroll
            for (int j = 0; j < 4; ++j) {
                const int row = wn * 64 + j * 16 + l16;
                const int idx = row * 16 + ((ks * 4 + quad) ^ (row & 15));
                bfr[j] = *(const bf16x8*)((const char*)Bs + idx * 16);
            }
            #pragma unroll
            for (int i = 0; i < 4; ++i)
                #pragma unroll
                for (int j = 0; j < 4; ++j)
                    acc[i][j] = __builtin_amdgcn_mfma_f32_16x16x32_bf16(af[i], bfr[j], acc[i][j], 0, 0, 0);
        }
        __syncthreads();
    }

    // epilogue: C/D layout col=l16 (n-dim), row=quad*4+reg (m-dim); write out[n*LDO+m]
    #pragma unroll
    for (int i = 0; i < 4; ++i) {
        const int mb = m0 + wm * 64 + i * 16 + quad * 4;
        f32x4 bb = {0.f, 0.f, 0.f, 0.f};
        if constexpr (BIAS) bb = *(const f32x4*)(bias + mb);
        #pragma unroll
        for (int j = 0; j < 4; ++j) {
            const int n = n0 + wn * 64 + j * 16 + l16;
            f32x4 v = acc[i][j];
            if constexpr (BIAS) v += bb;
            if constexpr (RELU) {
                v.x = v.x > 0.f ? v.x : 0.f;
                v.y = v.y > 0.f ? v.y : 0.f;
                v.z = v.z > 0.f ? v.z : 0.f;
                v.w = v.w > 0.f ? v.w : 0.f;
            }
            if constexpr (sizeof(OT) == 4) {
                *(f32x4*)((float*)out + (size_t)n * LDO + mb) = v;
            } else {
                u16x4 o;
                o.x = f2bf(v.x); o.y = f2bf(v.y); o.z = f2bf(v.z); o.w = f2bf(v.w);
                *(u16x4*)((unsigned short*)out + (size_t)n * LDO + mb) = o;
            }
        }
    }
}

extern "C" void kernel_launch(void* const* d_in, const int* in_sizes, int n_in,
                              void* d_out, int out_size, void* d_ws, size_t ws_size,
                              hipStream_t stream) {
    (void)in_sizes; (void)n_in; (void)out_size; (void)ws_size;
    const float* X   = (const float*)d_in[0];
    const float* adj = (const float*)d_in[1];
    const float* W0  = (const float*)d_in[2];
    const float* b0  = (const float*)d_in[3];
    const float* W1  = (const float*)d_in[4];
    const float* b1  = (const float*)d_in[5];
    const float* W2  = (const float*)d_in[6];
    const float* b2  = (const float*)d_in[7];
    float* out = (float*)d_out;

    // workspace layout (bf16): adjB | bufH (X/h, node-major) | tmpT (feat-major) | Wt x3
    char* ws = (char*)d_ws;
    const size_t SZ = 16777216;  // 32*512*512*2
    unsigned short* adjB = (unsigned short*)(ws);
    unsigned short* bufH = (unsigned short*)(ws + SZ);
    unsigned short* tmpT = (unsigned short*)(ws + 2 * SZ);
    unsigned short* Wt   = (unsigned short*)(ws + 3 * SZ);
    const unsigned short* W0t = Wt;
    const unsigned short* W1t = Wt + 262144;
    const unsigned short* W2t = Wt + 2 * 262144;

    prep_kernel<<<16384 + 768, 256, 0, stream>>>(X, adj, W0, W1, W2, bufH, adjB, Wt);

    const long BATCH = 512L * 512L;

    // layer 0: tmpT[e][node] = (h @ W0);  h = relu(adj @ tmp + b0) node-major
    gemm_abT_ct<512, 512, 16384, false, false, unsigned short>
        <<<dim3(128, 4, 1), 256, 0, stream>>>(bufH, W0t, tmpT, nullptr, 0, 0, 0);
    gemm_abT_ct<16384, 512, 512, true, true, unsigned short>
        <<<dim3(4, 4, 32), 256, 0, stream>>>(tmpT, adjB, bufH, b0, 512, BATCH, BATCH);
    // layer 1
    gemm_abT_ct<512, 512, 16384, false, false, unsigned short>
        <<<dim3(128, 4, 1), 256, 0, stream>>>(bufH, W1t, tmpT, nullptr, 0, 0, 0);
    gemm_abT_ct<16384, 512, 512, true, true, unsigned short>
        <<<dim3(4, 4, 32), 256, 0, stream>>>(tmpT, adjB, bufH, b1, 512, BATCH, BATCH);
    // layer 2 (no relu, fp32 out)
    gemm_abT_ct<512, 512, 16384, false, false, unsigned short>
        <<<dim3(128, 4, 1), 256, 0, stream>>>(bufH, W2t, tmpT, nullptr, 0, 0, 0);
    gemm_abT_ct<16384, 512, 512, true, false, float>
        <<<dim3(4, 4, 32), 256, 0, stream>>>(tmpT, adjB, out, b2, 512, BATCH, BATCH);
}